// Round 5
// baseline (350.000 us; speedup 1.0000x reference)
//
#include <hip/hip_runtime.h>
#include <math.h>

namespace {
constexpr int KF  = 1152;   // padded feature dim (1120 used + 32 zeros)
constexpr int RPB = 4;      // rows per k_feat block
}

typedef __bf16 v8bf __attribute__((ext_vector_type(8)));
typedef float  v4f  __attribute__((ext_vector_type(4)));

__device__ __forceinline__ unsigned short f2bf(float f) {
    union { float f; unsigned u; } v; v.f = f;
    unsigned r = v.u + 0x7FFFu + ((v.u >> 16) & 1u);
    return (unsigned short)(r >> 16);
}

__device__ __forceinline__ v8bf as_v8bf(uint4 u) {
    union { uint4 u; v8bf b; } c; c.u = u; return c.b;
}

// ---------------------------------------------------------------------------
// K1: per-row feature builder. 4 rows/block, 512 threads, grid 512
// (2 blocks/CU = 16 waves/CU).
// x -> h = silu(x@w1+b1) -> L (clamp/tril/softplus) -> G=L L^T -> u=Gx, c=x'Gx
// Features (bf16): A (Q rows): [G*2offdiag | outer(x) | u | x | 0pad]
//                  B (K rows): [outer(x) | G*2offdiag | -2x | -2u | 0pad]
// giving  A_n . B_m + cA_n + cB_m = 2*dist^2; c kept fp32.
// ---------------------------------------------------------------------------
__global__ __launch_bounds__(512) void k_feat(
    const float* __restrict__ Q, const float* __restrict__ K,
    const float* __restrict__ w1, const float* __restrict__ b1,
    const float* __restrict__ w2, const float* __restrict__ b2,
    unsigned short* __restrict__ featA, unsigned short* __restrict__ featB,
    float* __restrict__ cOut)
{
    __shared__ __attribute__((aligned(16))) float x_s[RPB][32];
    __shared__ __attribute__((aligned(16))) float h_s[RPB][64];
    __shared__ __attribute__((aligned(16))) float L_s[RPB][32][36];
    __shared__ __attribute__((aligned(16))) float G_s[RPB][528];   // col-major packed
    __shared__ __attribute__((aligned(16))) float u_s[RPB][32];
    __shared__ unsigned short tri_s[528];                          // (i<<8)|j

    const int t  = threadIdx.x;
    const int g0 = blockIdx.x * RPB;

    // ---- triangular index table (once per block). NOTE: strided loop — block
    // has 512 threads but the table has 528 entries (R4 bug: `if (t<528)` left
    // tri_s[512..527] uninitialized).
    for (int pr = t; pr < 528; pr += 512) {
        int j = (int)((65.0f - sqrtf(4225.0f - 8.0f * (float)pr)) * 0.5f);
        while (j > 0 && j * (65 - j) / 2 > pr) --j;
        while ((j + 1) * (64 - j) / 2 <= pr) ++j;
        int i = j + (pr - j * (65 - j) / 2);
        tri_s[pr] = (unsigned short)((i << 8) | j);
    }
    // ---- load x (4 rows x 32)
    if (t < RPB * 32) {
        int r = t >> 5, i = t & 31;
        int g = g0 + r;
        const float* src = (g < 1024) ? (Q + (size_t)g * 32)
                                      : (K + (size_t)(g - 1024) * 32);
        x_s[r][i] = src[i];
    }
    __syncthreads();

    // ---- h = silu(x @ w1 + b1): 256 outputs
    if (t < RPB * 64) {
        int r = t >> 6, j = t & 63;
        float z = b1[j];
        #pragma unroll
        for (int i = 0; i < 32; ++i) z = fmaf(x_s[r][i], w1[i * 64 + j], z);
        h_s[r][j] = z / (1.0f + __expf(-z));
    }
    __syncthreads();

    // ---- raw = h @ w2 + b2 -> L.
    // Thread (q = t&255, rp = t>>8) owns p-quad [4q,4q+4) x rows {2rp, 2rp+1}.
    {
        const int q  = t & 255;
        const int rp = t >> 8;          // 0 or 1
        const int p4 = q * 4;
        float acc[2][4];
        float4 bq = *(const float4*)&b2[p4];
        #pragma unroll
        for (int r = 0; r < 2; ++r) {
            acc[r][0] = bq.x; acc[r][1] = bq.y; acc[r][2] = bq.z; acc[r][3] = bq.w;
        }
        for (int jb = 0; jb < 8; ++jb) {
            float h8[2][8];
            #pragma unroll
            for (int r = 0; r < 2; ++r) {
                *(float4*)&h8[r][0] = *(const float4*)&h_s[2 * rp + r][jb * 8 + 0];
                *(float4*)&h8[r][4] = *(const float4*)&h_s[2 * rp + r][jb * 8 + 4];
            }
            #pragma unroll
            for (int jj = 0; jj < 8; ++jj) {
                float4 w = *(const float4*)&w2[(size_t)(jb * 8 + jj) * 1024 + p4];
                #pragma unroll
                for (int r = 0; r < 2; ++r) {
                    acc[r][0] = fmaf(h8[r][jj], w.x, acc[r][0]);
                    acc[r][1] = fmaf(h8[r][jj], w.y, acc[r][1]);
                    acc[r][2] = fmaf(h8[r][jj], w.z, acc[r][2]);
                    acc[r][3] = fmaf(h8[r][jj], w.w, acc[r][3]);
                }
            }
        }
        const int i  = p4 >> 5;
        const int j0 = p4 & 31;
        #pragma unroll
        for (int r = 0; r < 2; ++r) {
            float4 lv;
            float* lvp = (float*)&lv;
            #pragma unroll
            for (int e = 0; e < 4; ++e) {
                int j = j0 + e;
                float raw = acc[r][e];
                float ex = __expf(0.4f * raw);
                float c5 = 5.0f * (ex - 1.0f) / (ex + 1.0f);   // 5*tanh(raw/5)
                float val;
                if (i < j)       val = 0.0f;
                else if (i == j) { float z = c5 + 1.0f; val = log1pf(__expf(z)) + 1e-4f; }
                else             val = c5;
                lvp[e] = val;
            }
            *(float4*)&L_s[2 * rp + r][i][j0] = lv;
        }
    }
    __syncthreads();

    // ---- G = L L^T (lower triangle, packed column-major)
    for (int idx = t; idx < RPB * 528; idx += 512) {
        int r  = idx / 528;
        int pr = idx - r * 528;
        int tv = tri_s[pr];
        int i = tv >> 8, j = tv & 255;
        const float* Li = &L_s[r][i][0];
        const float* Lj = &L_s[r][j][0];
        float s = 0.0f;
        int nf = (j + 1) >> 2;
        for (int qq = 0; qq < nf; ++qq) {
            float4 a  = *(const float4*)&Li[qq * 4];
            float4 bb = *(const float4*)&Lj[qq * 4];
            s += a.x * bb.x + a.y * bb.y + a.z * bb.z + a.w * bb.w;
        }
        for (int tt = nf * 4; tt <= j; ++tt) s = fmaf(Li[tt], Lj[tt], s);
        G_s[r][pr] = s;
    }
    __syncthreads();

    // ---- u = G x
    if (t < RPB * 32) {
        int r = t >> 5, i = t & 31;
        float s = 0.0f;
        #pragma unroll
        for (int j = 0; j < 32; ++j) {
            float gv = (j <= i) ? G_s[r][j * (65 - j) / 2 + i - j]
                                : G_s[r][i * (65 - i) / 2 + j - i];
            s = fmaf(gv, x_s[r][j], s);
        }
        u_s[r][i] = s;
    }
    __syncthreads();

    // ---- c = u . x
    if (t < RPB) {
        float s = 0.0f;
        #pragma unroll
        for (int i = 0; i < 32; ++i) s = fmaf(u_s[t][i], x_s[t][i], s);
        cOut[g0 + t] = s;
    }

    // ---- feature write: quads of 4 bf16, packed uint2 stores (coalesced)
    for (int idx = t; idx < RPB * (KF / 4); idx += 512) {
        int r   = idx / (KF / 4);
        int q   = idx - r * (KF / 4);
        int pos = q * 4;
        int g   = g0 + r;
        bool isA = (g < 1024);
        unsigned short* dst = isA ? (featA + (size_t)g * KF)
                                  : (featB + (size_t)(g - 1024) * KF);
        unsigned short ev[4];
        #pragma unroll
        for (int e = 0; e < 4; ++e) {
            int p = pos + e;
            float va;
            if (p < 1056) {
                int pr = (p < 528) ? p : p - 528;
                bool wantG = (p < 528) ? isA : !isA;
                int tv = tri_s[pr];
                int i = tv >> 8, j = tv & 255;
                float gv = G_s[r][pr] * ((i == j) ? 1.0f : 2.0f);
                float ov = x_s[r][i] * x_s[r][j];
                va = wantG ? gv : ov;
            } else if (p < 1088) {
                int i = p - 1056;
                va = isA ? u_s[r][i] : -2.0f * x_s[r][i];
            } else if (p < 1120) {
                int i = p - 1088;
                va = isA ? x_s[r][i] : -2.0f * u_s[r][i];
            } else {
                va = 0.0f;   // ws re-poisoned 0xAA — pad must be written
            }
            ev[e] = f2bf(va);
        }
        uint2 w;
        w.x = (unsigned)ev[0] | ((unsigned)ev[1] << 16);
        w.y = (unsigned)ev[2] | ((unsigned)ev[3] << 16);
        *(uint2*)(dst + pos) = w;
    }
}

// ---------------------------------------------------------------------------
// K2: out = sqrt(clip(0.5*(cA+cB+A.B))). One wave per 16x32 tile (1024 blocks
// = 4 waves/CU), NO LDS: fragments are row-contiguous 16B global reads with a
// depth-3 register prefetch pipeline, no barriers.
// ---------------------------------------------------------------------------
__global__ __launch_bounds__(64) void k_gemm(
    const unsigned short* __restrict__ featA,
    const unsigned short* __restrict__ featB,
    const float* __restrict__ cOut,
    float* __restrict__ out)
{
    const int lane = threadIdx.x;
    const int m0 = blockIdx.x * 32;
    const int n0 = blockIdx.y * 16;
    const int b  = blockIdx.z;
    const int fr = lane & 15;
    const int fq = lane >> 4;

    const unsigned short* pA0 = featA + (size_t)(b * 512 + n0 + fr) * KF + fq * 8;
    const unsigned short* pB0 = featB + (size_t)(b * 512 + m0 + fr) * KF + fq * 8;
    const unsigned short* pB1 = pB0 + (size_t)16 * KF;

    v4f acc00 = {0,0,0,0}, acc01 = {0,0,0,0};

    uint4 bA0[3], bB0[3], bB1[3];
    #pragma unroll
    for (int s = 0; s < 3; ++s) {
        bA0[s] = *(const uint4*)(pA0 + s * 32);
        bB0[s] = *(const uint4*)(pB0 + s * 32);
        bB1[s] = *(const uint4*)(pB1 + s * 32);
    }

    for (int ks = 0; ks < 36; ks += 3) {
        #pragma unroll
        for (int s = 0; s < 3; ++s) {
            v8bf a0  = as_v8bf(bA0[s]);
            v8bf b0v = as_v8bf(bB0[s]);
            v8bf b1v = as_v8bf(bB1[s]);
            int kn = ks + s + 3;
            if (kn < 36) {
                bA0[s] = *(const uint4*)(pA0 + kn * 32);
                bB0[s] = *(const uint4*)(pB0 + kn * 32);
                bB1[s] = *(const uint4*)(pB1 + kn * 32);
            }
            acc00 = __builtin_amdgcn_mfma_f32_16x16x32_bf16(a0, b0v, acc00, 0, 0, 0);
            acc01 = __builtin_amdgcn_mfma_f32_16x16x32_bf16(a0, b1v, acc01, 0, 0, 0);
        }
    }

    // epilogue: D row = n0 + (lane>>4)*4+v, cols m0+colm and m0+16+colm
    const int colm = lane & 15;
    const float cB_0 = cOut[1024 + b * 512 + m0 + colm];
    const float cB_1 = cOut[1024 + b * 512 + m0 + 16 + colm];
    const int rbase = lane >> 4;
    #pragma unroll
    for (int v = 0; v < 4; ++v) {
        int n = n0 + rbase * 4 + v;
        float cA = cOut[b * 512 + n];
        float d0 = 0.5f * (acc00[v] + cA + cB_0);
        float d1 = 0.5f * (acc01[v] + cA + cB_1);
        d0 = fminf(fmaxf(d0, 1e-6f), 1e6f);
        d1 = fminf(fmaxf(d1, 1e-6f), 1e6f);
        size_t base = ((size_t)(b * 512 + n)) * 512;
        out[base + m0 + colm]      = sqrtf(d0);
        out[base + m0 + 16 + colm] = sqrtf(d1);
    }
}

// ---------------------------------------------------------------------------
extern "C" void kernel_launch(void* const* d_in, const int* in_sizes, int n_in,
                              void* d_out, int out_size, void* d_ws, size_t ws_size,
                              hipStream_t stream)
{
    const float* Q  = (const float*)d_in[0];
    const float* K  = (const float*)d_in[1];
    const float* w1 = (const float*)d_in[2];
    const float* b1 = (const float*)d_in[3];
    const float* w2 = (const float*)d_in[4];
    const float* b2 = (const float*)d_in[5];
    float* out = (float*)d_out;

    unsigned short* featA = (unsigned short*)d_ws;            // [1024][1152] bf16
    unsigned short* featB = featA + (size_t)1024 * KF;        // [1024][1152] bf16
    float* cOut = (float*)(featB + (size_t)1024 * KF);        // [2048] fp32

    k_feat<<<dim3(2048 / RPB), dim3(512), 0, stream>>>(Q, K, w1, b1, w2, b2, featA, featB, cOut);
    k_gemm<<<dim3(16, 32, 2), dim3(64), 0, stream>>>(featA, featB, cOut, out);
}

// Round 6
// 145.945 us; speedup vs baseline: 2.3982x; 2.3982x over previous
//
#include <hip/hip_runtime.h>
#include <math.h>

namespace {
constexpr int KF  = 1152;   // padded feature dim (1120 used + 32 zeros)
constexpr int RPB = 2;      // rows per k_feat block (256 threads, grid 1024)
}

typedef __bf16 v8bf __attribute__((ext_vector_type(8)));
typedef float  v4f  __attribute__((ext_vector_type(4)));

__device__ __forceinline__ unsigned short f2bf(float f) {
    union { float f; unsigned u; } v; v.f = f;
    unsigned r = v.u + 0x7FFFu + ((v.u >> 16) & 1u);
    return (unsigned short)(r >> 16);
}

__device__ __forceinline__ v8bf as_v8bf(uint4 u) {
    union { uint4 u; v8bf b; } c; c.u = u; return c.b;
}

// ---------------------------------------------------------------------------
// K1: per-row feature builder. 2 rows/block, 256 threads, grid 1024
// (4 blocks/CU = 16 waves/CU; LDS ~15.6 KB; VGPR ~88 -> NO spill.
//  R5 lesson: 512-thread blocks made the compiler cap VGPRs at 128 and spill
//  the w2-loop register arrays -> 846 MB scratch traffic, 10x regression.)
// x -> h = silu(x@w1+b1) -> L (clamp/tril/softplus) -> G=L L^T -> u=Gx, c=x'Gx
// Features (bf16): A (Q rows): [G*2offdiag | outer(x) | u | x | 0pad]
//                  B (K rows): [outer(x) | G*2offdiag | -2x | -2u | 0pad]
// giving  A_n . B_m + cA_n + cB_m = 2*dist^2; c kept fp32.
// ---------------------------------------------------------------------------
__global__ __launch_bounds__(256) void k_feat(
    const float* __restrict__ Q, const float* __restrict__ K,
    const float* __restrict__ w1, const float* __restrict__ b1,
    const float* __restrict__ w2, const float* __restrict__ b2,
    unsigned short* __restrict__ featA, unsigned short* __restrict__ featB,
    float* __restrict__ cOut)
{
    __shared__ __attribute__((aligned(16))) float x_s[RPB][32];
    __shared__ __attribute__((aligned(16))) float h_s[RPB][64];
    __shared__ __attribute__((aligned(16))) float L_s[RPB][32][36];
    __shared__ __attribute__((aligned(16))) float G_s[RPB][528];   // col-major packed
    __shared__ __attribute__((aligned(16))) float u_s[RPB][32];
    __shared__ unsigned short tri_s[528];                          // (i<<8)|j

    const int t  = threadIdx.x;
    const int g0 = blockIdx.x * RPB;

    // ---- triangular index table (once per block; STRIDED — table > blockDim)
    for (int pr = t; pr < 528; pr += 256) {
        int j = (int)((65.0f - sqrtf(4225.0f - 8.0f * (float)pr)) * 0.5f);
        while (j > 0 && j * (65 - j) / 2 > pr) --j;
        while ((j + 1) * (64 - j) / 2 <= pr) ++j;
        int i = j + (pr - j * (65 - j) / 2);
        tri_s[pr] = (unsigned short)((i << 8) | j);
    }
    // ---- load x (2 rows x 32)
    if (t < RPB * 32) {
        int r = t >> 5, i = t & 31;
        int g = g0 + r;
        const float* src = (g < 1024) ? (Q + (size_t)g * 32)
                                      : (K + (size_t)(g - 1024) * 32);
        x_s[r][i] = src[i];
    }
    __syncthreads();

    // ---- h = silu(x @ w1 + b1): 128 outputs
    if (t < RPB * 64) {
        int r = t >> 6, j = t & 63;
        float z = b1[j];
        #pragma unroll
        for (int i = 0; i < 32; ++i) z = fmaf(x_s[r][i], w1[i * 64 + j], z);
        h_s[r][j] = z / (1.0f + __expf(-z));
    }
    __syncthreads();

    // ---- raw = h @ w2 + b2 -> L.  Thread t owns p-quad [4t,4t+4), both rows.
    {
        const int p4 = t * 4;
        float acc[RPB][4];
        float4 bq = *(const float4*)&b2[p4];
        #pragma unroll
        for (int r = 0; r < RPB; ++r) {
            acc[r][0] = bq.x; acc[r][1] = bq.y; acc[r][2] = bq.z; acc[r][3] = bq.w;
        }
        for (int jb = 0; jb < 8; ++jb) {
            float h8[RPB][8];
            #pragma unroll
            for (int r = 0; r < RPB; ++r) {
                *(float4*)&h8[r][0] = *(const float4*)&h_s[r][jb * 8 + 0];
                *(float4*)&h8[r][4] = *(const float4*)&h_s[r][jb * 8 + 4];
            }
            #pragma unroll
            for (int jj = 0; jj < 8; ++jj) {
                float4 w = *(const float4*)&w2[(size_t)(jb * 8 + jj) * 1024 + p4];
                #pragma unroll
                for (int r = 0; r < RPB; ++r) {
                    acc[r][0] = fmaf(h8[r][jj], w.x, acc[r][0]);
                    acc[r][1] = fmaf(h8[r][jj], w.y, acc[r][1]);
                    acc[r][2] = fmaf(h8[r][jj], w.z, acc[r][2]);
                    acc[r][3] = fmaf(h8[r][jj], w.w, acc[r][3]);
                }
            }
        }
        const int i  = p4 >> 5;
        const int j0 = p4 & 31;
        #pragma unroll
        for (int r = 0; r < RPB; ++r) {
            float4 lv;
            float* lvp = (float*)&lv;
            #pragma unroll
            for (int e = 0; e < 4; ++e) {
                int j = j0 + e;
                float raw = acc[r][e];
                float ex = __expf(0.4f * raw);
                float c5 = 5.0f * (ex - 1.0f) / (ex + 1.0f);   // 5*tanh(raw/5)
                float val;
                if (i < j)       val = 0.0f;
                else if (i == j) { float z = c5 + 1.0f; val = log1pf(__expf(z)) + 1e-4f; }
                else             val = c5;
                lvp[e] = val;
            }
            *(float4*)&L_s[r][i][j0] = lv;
        }
    }
    __syncthreads();

    // ---- G = L L^T (lower triangle, packed column-major)
    for (int idx = t; idx < RPB * 528; idx += 256) {
        int r  = idx / 528;
        int pr = idx - r * 528;
        int tv = tri_s[pr];
        int i = tv >> 8, j = tv & 255;
        const float* Li = &L_s[r][i][0];
        const float* Lj = &L_s[r][j][0];
        float s = 0.0f;
        int nf = (j + 1) >> 2;
        for (int qq = 0; qq < nf; ++qq) {
            float4 a  = *(const float4*)&Li[qq * 4];
            float4 bb = *(const float4*)&Lj[qq * 4];
            s += a.x * bb.x + a.y * bb.y + a.z * bb.z + a.w * bb.w;
        }
        for (int tt = nf * 4; tt <= j; ++tt) s = fmaf(Li[tt], Lj[tt], s);
        G_s[r][pr] = s;
    }
    __syncthreads();

    // ---- u = G x
    if (t < RPB * 32) {
        int r = t >> 5, i = t & 31;
        float s = 0.0f;
        #pragma unroll
        for (int j = 0; j < 32; ++j) {
            float gv = (j <= i) ? G_s[r][j * (65 - j) / 2 + i - j]
                                : G_s[r][i * (65 - i) / 2 + j - i];
            s = fmaf(gv, x_s[r][j], s);
        }
        u_s[r][i] = s;
    }
    __syncthreads();

    // ---- c = u . x
    if (t < RPB) {
        float s = 0.0f;
        #pragma unroll
        for (int i = 0; i < 32; ++i) s = fmaf(u_s[t][i], x_s[t][i], s);
        cOut[g0 + t] = s;
    }

    // ---- feature write: quads of 4 bf16, packed uint2 stores (coalesced)
    for (int idx = t; idx < RPB * (KF / 4); idx += 256) {
        int r   = idx / (KF / 4);
        int q   = idx - r * (KF / 4);
        int pos = q * 4;
        int g   = g0 + r;
        bool isA = (g < 1024);
        unsigned short* dst = isA ? (featA + (size_t)g * KF)
                                  : (featB + (size_t)(g - 1024) * KF);
        unsigned short ev[4];
        #pragma unroll
        for (int e = 0; e < 4; ++e) {
            int p = pos + e;
            float va;
            if (p < 1056) {
                int pr = (p < 528) ? p : p - 528;
                bool wantG = (p < 528) ? isA : !isA;
                int tv = tri_s[pr];
                int i = tv >> 8, j = tv & 255;
                float gv = G_s[r][pr] * ((i == j) ? 1.0f : 2.0f);
                float ov = x_s[r][i] * x_s[r][j];
                va = wantG ? gv : ov;
            } else if (p < 1088) {
                int i = p - 1056;
                va = isA ? u_s[r][i] : -2.0f * x_s[r][i];
            } else if (p < 1120) {
                int i = p - 1088;
                va = isA ? x_s[r][i] : -2.0f * u_s[r][i];
            } else {
                va = 0.0f;   // ws re-poisoned 0xAA — pad must be written
            }
            ev[e] = f2bf(va);
        }
        uint2 w;
        w.x = (unsigned)ev[0] | ((unsigned)ev[1] << 16);
        w.y = (unsigned)ev[2] | ((unsigned)ev[3] << 16);
        *(uint2*)(dst + pos) = w;
    }
}

// ---------------------------------------------------------------------------
// K2: out = sqrt(clip(0.5*(cA+cB+A.B))). One wave per 16x32 tile (1024 blocks
// = 4 waves/CU), NO LDS: fragments are row-contiguous 16B global reads with a
// depth-3 register prefetch pipeline, no barriers.  (Validated in R5.)
// ---------------------------------------------------------------------------
__global__ __launch_bounds__(64) void k_gemm(
    const unsigned short* __restrict__ featA,
    const unsigned short* __restrict__ featB,
    const float* __restrict__ cOut,
    float* __restrict__ out)
{
    const int lane = threadIdx.x;
    const int m0 = blockIdx.x * 32;
    const int n0 = blockIdx.y * 16;
    const int b  = blockIdx.z;
    const int fr = lane & 15;
    const int fq = lane >> 4;

    const unsigned short* pA0 = featA + (size_t)(b * 512 + n0 + fr) * KF + fq * 8;
    const unsigned short* pB0 = featB + (size_t)(b * 512 + m0 + fr) * KF + fq * 8;
    const unsigned short* pB1 = pB0 + (size_t)16 * KF;

    v4f acc00 = {0,0,0,0}, acc01 = {0,0,0,0};

    uint4 bA0[3], bB0[3], bB1[3];
    #pragma unroll
    for (int s = 0; s < 3; ++s) {
        bA0[s] = *(const uint4*)(pA0 + s * 32);
        bB0[s] = *(const uint4*)(pB0 + s * 32);
        bB1[s] = *(const uint4*)(pB1 + s * 32);
    }

    for (int ks = 0; ks < 36; ks += 3) {
        #pragma unroll
        for (int s = 0; s < 3; ++s) {
            v8bf a0  = as_v8bf(bA0[s]);
            v8bf b0v = as_v8bf(bB0[s]);
            v8bf b1v = as_v8bf(bB1[s]);
            int kn = ks + s + 3;
            if (kn < 36) {
                bA0[s] = *(const uint4*)(pA0 + kn * 32);
                bB0[s] = *(const uint4*)(pB0 + kn * 32);
                bB1[s] = *(const uint4*)(pB1 + kn * 32);
            }
            acc00 = __builtin_amdgcn_mfma_f32_16x16x32_bf16(a0, b0v, acc00, 0, 0, 0);
            acc01 = __builtin_amdgcn_mfma_f32_16x16x32_bf16(a0, b1v, acc01, 0, 0, 0);
        }
    }

    // epilogue: D row = n0 + (lane>>4)*4+v, cols m0+colm and m0+16+colm
    const int colm = lane & 15;
    const float cB_0 = cOut[1024 + b * 512 + m0 + colm];
    const float cB_1 = cOut[1024 + b * 512 + m0 + 16 + colm];
    const int rbase = lane >> 4;
    #pragma unroll
    for (int v = 0; v < 4; ++v) {
        int n = n0 + rbase * 4 + v;
        float cA = cOut[b * 512 + n];
        float d0 = 0.5f * (acc00[v] + cA + cB_0);
        float d1 = 0.5f * (acc01[v] + cA + cB_1);
        d0 = fminf(fmaxf(d0, 1e-6f), 1e6f);
        d1 = fminf(fmaxf(d1, 1e-6f), 1e6f);
        size_t base = ((size_t)(b * 512 + n)) * 512;
        out[base + m0 + colm]      = sqrtf(d0);
        out[base + m0 + 16 + colm] = sqrtf(d1);
    }
}

// ---------------------------------------------------------------------------
extern "C" void kernel_launch(void* const* d_in, const int* in_sizes, int n_in,
                              void* d_out, int out_size, void* d_ws, size_t ws_size,
                              hipStream_t stream)
{
    const float* Q  = (const float*)d_in[0];
    const float* K  = (const float*)d_in[1];
    const float* w1 = (const float*)d_in[2];
    const float* b1 = (const float*)d_in[3];
    const float* w2 = (const float*)d_in[4];
    const float* b2 = (const float*)d_in[5];
    float* out = (float*)d_out;

    unsigned short* featA = (unsigned short*)d_ws;            // [1024][1152] bf16
    unsigned short* featB = featA + (size_t)1024 * KF;        // [1024][1152] bf16
    float* cOut = (float*)(featB + (size_t)1024 * KF);        // [2048] fp32

    k_feat<<<dim3(2048 / RPB), dim3(256), 0, stream>>>(Q, K, w1, b1, w2, b2, featA, featB, cOut);
    k_gemm<<<dim3(16, 32, 2), dim3(64), 0, stream>>>(featA, featB, cOut, out);
}

// Round 7
// 105.925 us; speedup vs baseline: 3.3042x; 1.3778x over previous
//
#include <hip/hip_runtime.h>
#include <math.h>

namespace {
constexpr int KF  = 1152;   // padded feature dim (1120 used + 32 zeros)
constexpr int RPB = 2;      // rows per k_feat block (256 threads, grid 1024)
}

typedef __bf16 v8bf __attribute__((ext_vector_type(8)));
typedef float  v4f  __attribute__((ext_vector_type(4)));

__device__ __forceinline__ unsigned short f2bf(float f) {
    union { float f; unsigned u; } v; v.f = f;
    unsigned r = v.u + 0x7FFFu + ((v.u >> 16) & 1u);
    return (unsigned short)(r >> 16);
}

__device__ __forceinline__ v8bf as_v8bf(uint4 u) {
    union { uint4 u; v8bf b; } c; c.u = u; return c.b;
}

// ---------------------------------------------------------------------------
// K1: per-row feature builder. 2 rows/block, 256 threads, grid 1024.
// __launch_bounds__(256,4): R6 lesson — with an uncapped budget the compiler
// fully unrolled the w2 loop (VGPR 252 -> 2 waves/SIMD, 72 us). Cap at 128
// VGPR => 4 blocks/CU co-resident; `#pragma unroll 1` on the jb loop keeps
// ~8 float4 loads in flight so the cap is met without spill (R5 lesson:
// spill = FETCH_SIZE balloons to 100s of MB).
// x -> h = silu(x@w1+b1) -> L (clamp/tril/softplus) -> G=L L^T -> u=Gx, c=x'Gx
// Features (bf16): A (Q rows): [G*2offdiag | outer(x) | u | x | 0pad]
//                  B (K rows): [outer(x) | G*2offdiag | -2x | -2u | 0pad]
// giving  A_n . B_m + cA_n + cB_m = 2*dist^2; c kept fp32.
// ---------------------------------------------------------------------------
__global__ __launch_bounds__(256, 4) void k_feat(
    const float* __restrict__ Q, const float* __restrict__ K,
    const float* __restrict__ w1, const float* __restrict__ b1,
    const float* __restrict__ w2, const float* __restrict__ b2,
    unsigned short* __restrict__ featA, unsigned short* __restrict__ featB,
    float* __restrict__ cOut)
{
    __shared__ __attribute__((aligned(16))) float x_s[RPB][32];
    __shared__ __attribute__((aligned(16))) float h_s[RPB][64];
    __shared__ __attribute__((aligned(16))) float L_s[RPB][32][36];
    __shared__ __attribute__((aligned(16))) float G_s[RPB][528];   // col-major packed
    __shared__ __attribute__((aligned(16))) float u_s[RPB][32];
    __shared__ unsigned short tri_s[528];                          // (i<<8)|j

    const int t  = threadIdx.x;
    const int g0 = blockIdx.x * RPB;

    // ---- triangular index table (once per block; STRIDED — table > blockDim)
    for (int pr = t; pr < 528; pr += 256) {
        int j = (int)((65.0f - sqrtf(4225.0f - 8.0f * (float)pr)) * 0.5f);
        while (j > 0 && j * (65 - j) / 2 > pr) --j;
        while ((j + 1) * (64 - j) / 2 <= pr) ++j;
        int i = j + (pr - j * (65 - j) / 2);
        tri_s[pr] = (unsigned short)((i << 8) | j);
    }
    // ---- load x (2 rows x 32)
    if (t < RPB * 32) {
        int r = t >> 5, i = t & 31;
        int g = g0 + r;
        const float* src = (g < 1024) ? (Q + (size_t)g * 32)
                                      : (K + (size_t)(g - 1024) * 32);
        x_s[r][i] = src[i];
    }
    __syncthreads();

    // ---- h = silu(x @ w1 + b1): 128 outputs
    if (t < RPB * 64) {
        int r = t >> 6, j = t & 63;
        float z = b1[j];
        #pragma unroll
        for (int i = 0; i < 32; ++i) z = fmaf(x_s[r][i], w1[i * 64 + j], z);
        h_s[r][j] = z / (1.0f + __expf(-z));
    }
    __syncthreads();

    // ---- raw = h @ w2 + b2 -> L.  Thread t owns p-quad [4t,4t+4), both rows.
    {
        const int p4 = t * 4;
        float acc[RPB][4];
        float4 bq = *(const float4*)&b2[p4];
        #pragma unroll
        for (int r = 0; r < RPB; ++r) {
            acc[r][0] = bq.x; acc[r][1] = bq.y; acc[r][2] = bq.z; acc[r][3] = bq.w;
        }
        #pragma unroll 1
        for (int jb = 0; jb < 8; ++jb) {
            float h8[RPB][8];
            #pragma unroll
            for (int r = 0; r < RPB; ++r) {
                *(float4*)&h8[r][0] = *(const float4*)&h_s[r][jb * 8 + 0];
                *(float4*)&h8[r][4] = *(const float4*)&h_s[r][jb * 8 + 4];
            }
            #pragma unroll
            for (int jj = 0; jj < 8; ++jj) {
                float4 w = *(const float4*)&w2[(size_t)(jb * 8 + jj) * 1024 + p4];
                #pragma unroll
                for (int r = 0; r < RPB; ++r) {
                    acc[r][0] = fmaf(h8[r][jj], w.x, acc[r][0]);
                    acc[r][1] = fmaf(h8[r][jj], w.y, acc[r][1]);
                    acc[r][2] = fmaf(h8[r][jj], w.z, acc[r][2]);
                    acc[r][3] = fmaf(h8[r][jj], w.w, acc[r][3]);
                }
            }
        }
        const int i  = p4 >> 5;
        const int j0 = p4 & 31;
        #pragma unroll
        for (int r = 0; r < RPB; ++r) {
            float4 lv;
            float* lvp = (float*)&lv;
            #pragma unroll
            for (int e = 0; e < 4; ++e) {
                int j = j0 + e;
                float raw = acc[r][e];
                float ex = __expf(0.4f * raw);
                float c5 = 5.0f * (ex - 1.0f) / (ex + 1.0f);   // 5*tanh(raw/5)
                float val;
                if (i < j)       val = 0.0f;
                else if (i == j) { float z = c5 + 1.0f; val = log1pf(__expf(z)) + 1e-4f; }
                else             val = c5;
                lvp[e] = val;
            }
            *(float4*)&L_s[r][i][j0] = lv;
        }
    }
    __syncthreads();

    // ---- G = L L^T (lower triangle, packed column-major)
    for (int idx = t; idx < RPB * 528; idx += 256) {
        int r  = idx / 528;
        int pr = idx - r * 528;
        int tv = tri_s[pr];
        int i = tv >> 8, j = tv & 255;
        const float* Li = &L_s[r][i][0];
        const float* Lj = &L_s[r][j][0];
        float s = 0.0f;
        int nf = (j + 1) >> 2;
        for (int qq = 0; qq < nf; ++qq) {
            float4 a  = *(const float4*)&Li[qq * 4];
            float4 bb = *(const float4*)&Lj[qq * 4];
            s += a.x * bb.x + a.y * bb.y + a.z * bb.z + a.w * bb.w;
        }
        for (int tt = nf * 4; tt <= j; ++tt) s = fmaf(Li[tt], Lj[tt], s);
        G_s[r][pr] = s;
    }
    __syncthreads();

    // ---- u = G x
    if (t < RPB * 32) {
        int r = t >> 5, i = t & 31;
        float s = 0.0f;
        #pragma unroll
        for (int j = 0; j < 32; ++j) {
            float gv = (j <= i) ? G_s[r][j * (65 - j) / 2 + i - j]
                                : G_s[r][i * (65 - i) / 2 + j - i];
            s = fmaf(gv, x_s[r][j], s);
        }
        u_s[r][i] = s;
    }
    __syncthreads();

    // ---- c = u . x
    if (t < RPB) {
        float s = 0.0f;
        #pragma unroll
        for (int i = 0; i < 32; ++i) s = fmaf(u_s[t][i], x_s[t][i], s);
        cOut[g0 + t] = s;
    }

    // ---- feature write: quads of 4 bf16, packed uint2 stores (coalesced)
    for (int idx = t; idx < RPB * (KF / 4); idx += 256) {
        int r   = idx / (KF / 4);
        int q   = idx - r * (KF / 4);
        int pos = q * 4;
        int g   = g0 + r;
        bool isA = (g < 1024);
        unsigned short* dst = isA ? (featA + (size_t)g * KF)
                                  : (featB + (size_t)(g - 1024) * KF);
        unsigned short ev[4];
        #pragma unroll
        for (int e = 0; e < 4; ++e) {
            int p = pos + e;
            float va;
            if (p < 1056) {
                int pr = (p < 528) ? p : p - 528;
                bool wantG = (p < 528) ? isA : !isA;
                int tv = tri_s[pr];
                int i = tv >> 8, j = tv & 255;
                float gv = G_s[r][pr] * ((i == j) ? 1.0f : 2.0f);
                float ov = x_s[r][i] * x_s[r][j];
                va = wantG ? gv : ov;
            } else if (p < 1088) {
                int i = p - 1056;
                va = isA ? u_s[r][i] : -2.0f * x_s[r][i];
            } else if (p < 1120) {
                int i = p - 1088;
                va = isA ? x_s[r][i] : -2.0f * u_s[r][i];
            } else {
                va = 0.0f;   // ws re-poisoned 0xAA — pad must be written
            }
            ev[e] = f2bf(va);
        }
        uint2 w;
        w.x = (unsigned)ev[0] | ((unsigned)ev[1] << 16);
        w.y = (unsigned)ev[2] | ((unsigned)ev[3] << 16);
        *(uint2*)(dst + pos) = w;
    }
}

// ---------------------------------------------------------------------------
// K2: out = sqrt(clip(0.5*(cA+cB+A.B))). One wave per 16x32 tile (1024 blocks
// = 4 waves/CU), NO LDS: fragments are row-contiguous 16B global reads with a
// depth-3 register prefetch pipeline, no barriers.  (Validated R5/R6.)
// ---------------------------------------------------------------------------
__global__ __launch_bounds__(64) void k_gemm(
    const unsigned short* __restrict__ featA,
    const unsigned short* __restrict__ featB,
    const float* __restrict__ cOut,
    float* __restrict__ out)
{
    const int lane = threadIdx.x;
    const int m0 = blockIdx.x * 32;
    const int n0 = blockIdx.y * 16;
    const int b  = blockIdx.z;
    const int fr = lane & 15;
    const int fq = lane >> 4;

    const unsigned short* pA0 = featA + (size_t)(b * 512 + n0 + fr) * KF + fq * 8;
    const unsigned short* pB0 = featB + (size_t)(b * 512 + m0 + fr) * KF + fq * 8;
    const unsigned short* pB1 = pB0 + (size_t)16 * KF;

    v4f acc00 = {0,0,0,0}, acc01 = {0,0,0,0};

    uint4 bA0[3], bB0[3], bB1[3];
    #pragma unroll
    for (int s = 0; s < 3; ++s) {
        bA0[s] = *(const uint4*)(pA0 + s * 32);
        bB0[s] = *(const uint4*)(pB0 + s * 32);
        bB1[s] = *(const uint4*)(pB1 + s * 32);
    }

    for (int ks = 0; ks < 36; ks += 3) {
        #pragma unroll
        for (int s = 0; s < 3; ++s) {
            v8bf a0  = as_v8bf(bA0[s]);
            v8bf b0v = as_v8bf(bB0[s]);
            v8bf b1v = as_v8bf(bB1[s]);
            int kn = ks + s + 3;
            if (kn < 36) {
                bA0[s] = *(const uint4*)(pA0 + kn * 32);
                bB0[s] = *(const uint4*)(pB0 + kn * 32);
                bB1[s] = *(const uint4*)(pB1 + kn * 32);
            }
            acc00 = __builtin_amdgcn_mfma_f32_16x16x32_bf16(a0, b0v, acc00, 0, 0, 0);
            acc01 = __builtin_amdgcn_mfma_f32_16x16x32_bf16(a0, b1v, acc01, 0, 0, 0);
        }
    }

    // epilogue: D row = n0 + (lane>>4)*4+v, cols m0+colm and m0+16+colm
    const int colm = lane & 15;
    const float cB_0 = cOut[1024 + b * 512 + m0 + colm];
    const float cB_1 = cOut[1024 + b * 512 + m0 + 16 + colm];
    const int rbase = lane >> 4;
    #pragma unroll
    for (int v = 0; v < 4; ++v) {
        int n = n0 + rbase * 4 + v;
        float cA = cOut[b * 512 + n];
        float d0 = 0.5f * (acc00[v] + cA + cB_0);
        float d1 = 0.5f * (acc01[v] + cA + cB_1);
        d0 = fminf(fmaxf(d0, 1e-6f), 1e6f);
        d1 = fminf(fmaxf(d1, 1e-6f), 1e6f);
        size_t base = ((size_t)(b * 512 + n)) * 512;
        out[base + m0 + colm]      = sqrtf(d0);
        out[base + m0 + 16 + colm] = sqrtf(d1);
    }
}

// ---------------------------------------------------------------------------
extern "C" void kernel_launch(void* const* d_in, const int* in_sizes, int n_in,
                              void* d_out, int out_size, void* d_ws, size_t ws_size,
                              hipStream_t stream)
{
    const float* Q  = (const float*)d_in[0];
    const float* K  = (const float*)d_in[1];
    const float* w1 = (const float*)d_in[2];
    const float* b1 = (const float*)d_in[3];
    const float* w2 = (const float*)d_in[4];
    const float* b2 = (const float*)d_in[5];
    float* out = (float*)d_out;

    unsigned short* featA = (unsigned short*)d_ws;            // [1024][1152] bf16
    unsigned short* featB = featA + (size_t)1024 * KF;        // [1024][1152] bf16
    float* cOut = (float*)(featB + (size_t)1024 * KF);        // [2048] fp32

    k_feat<<<dim3(2048 / RPB), dim3(256), 0, stream>>>(Q, K, w1, b1, w2, b2, featA, featB, cOut);
    k_gemm<<<dim3(16, 32, 2), dim3(64), 0, stream>>>(featA, featB, cOut, out);
}